// Round 14
// baseline (150.819 us; speedup 1.0000x reference)
//
#include <hip/hip_runtime.h>
#include <hip/hip_bf16.h>

// Problem constants
#define B_    4
#define N_    2048
#define INF_  256
#define OUTF_ 256
#define H_    8
#define NH_   32
#define BH_   (B_ * H_)          // 32
#define ROWS_ (B_ * N_)          // 8192 rows of Wh
#define VSZ_  (N_ * NH_)         // 65536 floats per (b,head) value chunk

typedef float  f32x4 __attribute__((ext_vector_type(4)));
typedef short  s16x8 __attribute__((ext_vector_type(8)));

static __device__ __forceinline__ short f2bf(float x) {
    union { __hip_bfloat16 b; unsigned short u; } cv;
    cv.b = __float2bfloat16(x);
    return (short)cv.u;
}

// ---------------------------------------------------------------------------
// Kernel 1: prep — fused bitpack + h->bf16 + W->bf16 B-frags. (unchanged)
// ---------------------------------------------------------------------------
__global__ __launch_bounds__(256) void prep(const int* __restrict__ adj,
                                            unsigned int* __restrict__ adjw,
                                            const float* __restrict__ h,
                                            const float* __restrict__ W,
                                            short* __restrict__ hb,
                                            short* __restrict__ Wf) {
    const int blk = blockIdx.x;
    const int tid = threadIdx.x;
    if (blk < 2048) {                       // ---- bitpack adj
        const int idx = blk * 256 + tid;    // 0 .. B*N*64-1
        const int4* p = (const int4*)(adj + (size_t)idx * 32);
        unsigned int w = 0;
#pragma unroll
        for (int q = 0; q < 8; ++q) {
            int4 v = p[q];
            w |= (v.x != 0 ? 1u : 0u) << (q * 4 + 0);
            w |= (v.y != 0 ? 1u : 0u) << (q * 4 + 1);
            w |= (v.z != 0 ? 1u : 0u) << (q * 4 + 2);
            w |= (v.w != 0 ? 1u : 0u) << (q * 4 + 3);
        }
        adjw[idx] = w;
    } else if (blk < 3072) {                // ---- h -> bf16 flat
        const int t = (blk - 2048) * 256 + tid;
        const float4* src = (const float4*)(h + (size_t)t * 8);
        float4 v0 = src[0], v1 = src[1];
        float vv[8] = {v0.x, v0.y, v0.z, v0.w, v1.x, v1.y, v1.z, v1.w};
        s16x8 o;
#pragma unroll
        for (int i = 0; i < 8; ++i) o[i] = f2bf(vv[i]);
        *(s16x8*)(hb + (size_t)t * 8) = o;
    } else {                                // ---- W -> bf16 B-fragments
        const int u = (blk - 3072) * 256 + tid;   // 0..8191
        const int lane = u & 63, nf = (u >> 6) & 15, kt = u >> 10;
        const float* src = W + (size_t)(kt * 32 + (lane >> 4) * 8) * 256 +
                           nf * 16 + (lane & 15);
        s16x8 o;
#pragma unroll
        for (int i = 0; i < 8; ++i) o[i] = f2bf(src[(size_t)i * 256]);
        *(s16x8*)(Wf + (size_t)u * 8) = o;
    }
}

// ---------------------------------------------------------------------------
// Kernel 2: gemm_stv — bf16 MFMA GEMM + fused epilogue (rS = exp(-0.8 s),
// tE = {exp(t), exp(0.2 t)}) + direct Vb scatter. (unchanged, passing)
// ---------------------------------------------------------------------------
__global__ __launch_bounds__(256) void gemm_stv(const short* __restrict__ hb,
                                                const short* __restrict__ Wf,
                                                const float* __restrict__ a,
                                                float* __restrict__ rS,
                                                float2* __restrict__ tE,
                                                short* __restrict__ Vb) {
    const int bm  = blockIdx.x * 64;
    const int bn4 = blockIdx.y * 4;
    const int tid = threadIdx.x;
    const int wv = tid >> 6, l = tid & 63;
    const int lr = l & 15, lg = l >> 4;
    const int arow = bm + wv * 16 + lr;

    f32x4 acc[4] = {};
    const s16x8* wf = (const s16x8*)Wf;
    const s16x8* ha = (const s16x8*)(hb + (size_t)arow * 256 + lg * 8);

#pragma unroll
    for (int kt = 0; kt < 8; ++kt) {
        s16x8 av = ha[kt * 4];
#pragma unroll
        for (int nf = 0; nf < 4; ++nf) {
            s16x8 b = wf[(size_t)(kt * 16 + bn4 + nf) * 64 + l];
            acc[nf] = __builtin_amdgcn_mfma_f32_16x16x32_bf16(av, b, acc[nf], 0, 0, 0);
        }
    }

    // ---- Vb scatter write (bf16 B-fragment layout)
    {
        const int bh  = bm >> 8;
        const int rr0 = (bm & 255) + wv * 16 + 4 * lg;
        short* vout = Vb + (size_t)bh * 65536;
#pragma unroll
        for (int nf = 0; nf < 4; ++nf) {
            const int nt = nf & 1;
            const int ch = (bn4 + nf) >> 1;
#pragma unroll
            for (int r = 0; r < 4; ++r) {
                const int rr = rr0 + r;
                vout[((rr >> 2) * 2 + nt) * 512 + ((rr & 3) * 16 + lr) * 8 + ch] =
                    f2bf(acc[nf][r]);
            }
        }
    }

    // ---- fused st epilogue
    const float a1lo = a[lr],      a1hi = a[16 + lr];
    const float a2lo = a[32 + lr], a2hi = a[48 + lr];
#pragma unroll
    for (int k = 0; k < 2; ++k) {
#pragma unroll
        for (int r = 0; r < 4; ++r) {
            float ps = acc[2 * k][r] * a1lo + acc[2 * k + 1][r] * a1hi;
            float pt = acc[2 * k][r] * a2lo + acc[2 * k + 1][r] * a2hi;
#pragma unroll
            for (int d = 1; d < 16; d <<= 1) {
                ps += __shfl_xor(ps, d);
                pt += __shfl_xor(pt, d);
            }
            if (lr == 0) {
                const int R  = bm + wv * 16 + 4 * lg + r;
                const int b  = R >> 11, rin = R & 2047;
                const int hh = rin >> 8, rr = rin & 255;
                const int n  = rr * 8 + (bn4 >> 1) + k;     // view-row in (b,h)
                const int g  = ((b * 8 + hh) << 11) + n;
                rS[g] = __expf(-0.8f * ps);
                tE[g] = make_float2(__expf(pt), __expf(0.2f * pt));
            }
        }
    }
}

// ---------------------------------------------------------------------------
// Kernel 3: attention partial — j-range split 2x (blockIdx.z), half LDS
// (17.2 KB) -> 8-9 blocks/CU for latency hiding. Writes UNNORMALIZED
// numerator/denominator partials; merge kernel finishes.
// ---------------------------------------------------------------------------
__global__ __launch_bounds__(256) void attn_part(const short* __restrict__ Vb,
                                                 const float* __restrict__ rS,
                                                 const float2* __restrict__ tE,
                                                 const unsigned int* __restrict__ adjw,
                                                 float* __restrict__ pnum,
                                                 float* __restrict__ pden) {
    const int bh = blockIdx.y;        // b*8+h
    const int b  = bh >> 3;
    const int i0 = blockIdx.x * 64;
    const int jz = blockIdx.z;        // j-half: tiles jz*32 .. jz*32+31
    const int tid = threadIdx.x;
    const int wv = tid >> 6;          // wave 0..3
    const int l  = tid & 63;
    const int lr = l & 15;            // A-frag row / D col
    const int lg = l >> 4;            // k-group 0..3

    __shared__ int    adjL[64][36];   // 9.2 KB (stride 144B, int4-aligned)
    __shared__ float4 ts4[512];       // 8 KB: this half's {Et,Et2} pairs

    {   // stage adj: 64 rows x 32 words (this j-half), 2 int4/thread
        const int4* ab4 = (const int4*)(adjw + ((size_t)(b * N_ + i0)) * 64 + jz * 32);
#pragma unroll
        for (int k = 0; k < 2; ++k) {
            const int idx4 = tid + k * 256;               // 0..511
            int4 v = ab4[(idx4 >> 3) * 16 + (idx4 & 7)];  // row stride 64 words
            *(int4*)&adjL[idx4 >> 3][(idx4 & 7) << 2] = v;
        }
    }
    {   // stage tE pairs for this half (512 float4)
        const float4* tsrc = (const float4*)(tE + (size_t)bh * N_) + jz * 512;
        ts4[tid]       = tsrc[tid];
        ts4[tid + 256] = tsrc[tid + 256];
    }
    const float rr_i = rS[(size_t)bh * N_ + i0 + wv * 16 + lr];
    __syncthreads();

    // ones-column B-frag: col 0 = 1.0, rest 0 (denominator MFMA)
    s16x8 bOnes;
#pragma unroll
    for (int i = 0; i < 8; ++i) bOnes[i] = (lr == 0) ? (short)0x3F80 : (short)0;

    const s16x8* vbz = (const s16x8*)(Vb + (size_t)bh * 65536) + (size_t)jz * 32 * 128;
    const int*    adjRow = &adjL[wv * 16 + lr][0];
    const float4* tsRow  = ts4 + lg * 4;

    f32x4 acc0 = {0.f, 0.f, 0.f, 0.f};
    f32x4 acc1 = {0.f, 0.f, 0.f, 0.f};
    f32x4 acc2 = {0.f, 0.f, 0.f, 0.f};

    auto tile = [&](int jtc, const s16x8& B0, const s16x8& B1) {
        const unsigned wsh = ((unsigned)adjRow[jtc]) >> (lg * 8);
        const float4* qp = tsRow + jtc * 16;
        float4 q0 = qp[0];
        float4 q1 = qp[1];
        float4 q2 = qp[2];
        float4 q3 = qp[3];
        float p[8];
        p[0] = fmaxf(q0.x, rr_i * q0.y);
        p[1] = fmaxf(q0.z, rr_i * q0.w);
        p[2] = fmaxf(q1.x, rr_i * q1.y);
        p[3] = fmaxf(q1.z, rr_i * q1.w);
        p[4] = fmaxf(q2.x, rr_i * q2.y);
        p[5] = fmaxf(q2.z, rr_i * q2.w);
        p[6] = fmaxf(q3.x, rr_i * q3.y);
        p[7] = fmaxf(q3.z, rr_i * q3.w);
        unsigned pu[8];
#pragma unroll
        for (int i = 0; i < 8; ++i) {
            const int m = ((int)(wsh << (31 - i))) >> 31;   // sext of bit i
            pu[i] = __float_as_uint(p[i]) & (unsigned)m;
        }
        union { unsigned u[4]; s16x8 v; } af;
#pragma unroll
        for (int q = 0; q < 4; ++q)
            asm("v_cvt_pk_bf16_f32 %0, %1, %2"
                : "=v"(af.u[q])
                : "v"(__uint_as_float(pu[2 * q])), "v"(__uint_as_float(pu[2 * q + 1])));
        acc0 = __builtin_amdgcn_mfma_f32_16x16x32_bf16(af.v, B0, acc0, 0, 0, 0);
        acc1 = __builtin_amdgcn_mfma_f32_16x16x32_bf16(af.v, B1, acc1, 0, 0, 0);
        acc2 = __builtin_amdgcn_mfma_f32_16x16x32_bf16(af.v, bOnes, acc2, 0, 0, 0);
    };

    s16x8 cb0 = vbz[l], cb1 = vbz[64 + l];
    // 32 local tiles: 24 with unconditional depth-1 prefetch + peeled tail 8
    for (int jt0 = 0; jt0 < 24; jt0 += 8) {
#pragma unroll
        for (int k = 0; k < 8; ++k) {
            const int jt = jt0 + k;
            s16x8 nb0 = vbz[(jt + 1) * 128 + l];
            s16x8 nb1 = vbz[(jt + 1) * 128 + 64 + l];
            tile(jt, cb0, cb1);
            cb0 = nb0; cb1 = nb1;
        }
    }
#pragma unroll
    for (int k = 0; k < 8; ++k) {
        const int jt = 24 + k;
        if (k < 7) {
            s16x8 nb0 = vbz[(jt + 1) * 128 + l];
            s16x8 nb1 = vbz[(jt + 1) * 128 + 64 + l];
            tile(jt, cb0, cb1);
            cb0 = nb0; cb1 = nb1;
        } else {
            tile(jt, cb0, cb1);
        }
    }

    // epilogue: write unnormalized partials
    float* pn = pnum + ((size_t)jz * BH_ * N_ + (size_t)bh * N_) * 32;
    float* pd = pden + (size_t)jz * BH_ * N_ + (size_t)bh * N_;
#pragma unroll
    for (int r = 0; r < 4; ++r) {
        const int rloc = 4 * lg + r;
        const int row = i0 + rloc + wv * 16;
        pn[(size_t)row * 32 + lr]      = acc0[r];
        pn[(size_t)row * 32 + 16 + lr] = acc1[r];
        if (lr == 0) pd[row] = acc2[r];   // lane lg*16 holds col 0 of row 4lg+r
    }
}

// ---------------------------------------------------------------------------
// Kernel 4: merge — out = elu((n0+n1)/(d0+d1)). 2M floats, 8 per thread.
// ---------------------------------------------------------------------------
__global__ __launch_bounds__(256) void merge(const float* __restrict__ pnum,
                                             const float* __restrict__ pden,
                                             float* __restrict__ out) {
    const int t = blockIdx.x * 256 + threadIdx.x;   // 0..262143
    const int row = t >> 2;                         // global view-row 0..65535
    const int c8 = (t & 3) * 8;
    const float* n0 = pnum + (size_t)row * 32 + c8;
    const float* n1 = pnum + (size_t)BH_ * N_ * 32 + (size_t)row * 32 + c8;
    const float ir = 1.0f / (pden[row] + pden[BH_ * N_ + row]);
    float4 a0 = *(const float4*)n0, a1 = *(const float4*)(n0 + 4);
    float4 b0 = *(const float4*)n1, b1 = *(const float4*)(n1 + 4);
    float o[8] = {a0.x + b0.x, a0.y + b0.y, a0.z + b0.z, a0.w + b0.w,
                  a1.x + b1.x, a1.y + b1.y, a1.z + b1.z, a1.w + b1.w};
#pragma unroll
    for (int i = 0; i < 8; ++i) {
        float v = o[i] * ir;
        o[i] = v > 0.f ? v : expm1f(v);
    }
    *(float4*)(out + (size_t)row * 32 + c8)     = *(float4*)&o[0];
    *(float4*)(out + (size_t)row * 32 + c8 + 4) = *(float4*)&o[4];
}

// ---------------------------------------------------------------------------
extern "C" void kernel_launch(void* const* d_in, const int* in_sizes, int n_in,
                              void* d_out, int out_size, void* d_ws, size_t ws_size,
                              hipStream_t stream) {
    const float* h   = (const float*)d_in[0];         // [4,2048,256]
    const int*   adj = (const int*)d_in[1];           // [4,2048,2048]
    const float* W   = (const float*)d_in[2];         // [256,256]
    const float* a   = (const float*)d_in[3];         // [64,1]
    float* out = (float*)d_out;                       // [4,2048,256] fp32

    char* ws = (char*)d_ws;
    float*  rS = (float*)ws;                                        // 256 KB slot
    float2* tE = (float2*)(ws + (size_t)BH_ * N_ * 8);              // 512 KB
    unsigned int* adjw = (unsigned int*)(ws + 2 * (size_t)BH_ * N_ * 8);  // 2 MB
    char* p2 = ws + 2 * (size_t)BH_ * N_ * 8 + (size_t)B_ * N_ * 64 * 4;
    short* Vb = (short*)p2;                                         // 4 MB
    short* hb = (short*)(p2 + (size_t)BH_ * VSZ_ * 2);              // 4 MB
    short* Wf = (short*)(p2 + (size_t)BH_ * VSZ_ * 2 + (size_t)ROWS_ * INF_ * 2); // 128 KB
    char* p3 = p2 + (size_t)BH_ * VSZ_ * 2 + (size_t)ROWS_ * INF_ * 2 + 8192 * 16;
    float* pnum = (float*)p3;                                       // 16 MB
    float* pden = (float*)(p3 + 2 * (size_t)BH_ * N_ * 32 * 4);     // 512 KB

    prep<<<3104, 256, 0, stream>>>(adj, adjw, h, W, hb, Wf);
    gemm_stv<<<dim3(ROWS_ / 64, OUTF_ / 64), 256, 0, stream>>>(hb, Wf, a, rS, tE, Vb);
    attn_part<<<dim3(N_ / 64, BH_, 2), 256, 0, stream>>>(Vb, rS, tE, adjw, pnum, pden);
    merge<<<1024, 256, 0, stream>>>(pnum, pden, out);
}